// Round 5
// baseline (219.994 us; speedup 1.0000x reference)
//
#include <hip/hip_runtime.h>
#include <cstdint>

#define A_DIM 1024
#define B_DIM 64
#define H_DIM 512
#define L_TXT 1024
#define L_IMG 256

typedef float f32x4 __attribute__((ext_vector_type(4)));

// ---------------- ws layout (float offsets) ----------------
// P1 : 4 mats * 4 kq * 64 * 1024 = 1,048,576   [offset 0; persists to k5b (g3/g4)]
// P4 : 1280 * 1024               = 1,310,720   [offset 1,048,576; dead after k34]
// P5 : 2 mats * 4 kq * 64 * 1024 =   524,288   [offset 1,048,576; reuses P4 region]
// p_all: 65,536 + 16,384         =    81,920   [offset 2,359,296]
// ctx  : 2 * 65,536              =   131,072   [offset 2,441,216]
// total = 2,572,288 floats ≈ 9.8 MB
#define WS_P1_OFF   0u
#define WS_P4_OFF   1048576u
#define WS_P5_OFF   1048576u
#define WS_PALL_OFF 2359296u
#define WS_CTX_OFF  2441216u

// d_out layout (floats): ctx_mm[0..65535], attn[65536..131071],
// attn_img[131072..147455], coverage[147456..212991], coverage_img[212992..229375]

__device__ __forceinline__ float ftanh(float x) {
  float xc = fminf(fmaxf(x, -10.f), 10.f);
  float t  = __expf(2.f * xc);
  return (t - 1.f) * __builtin_amdgcn_rcpf(t + 1.f);
}

// K1: partials of dec @ {W1..W4}. W rows loaded VECTOR-coalesced (lane = a/4),
// dec loaded as uniform sequential s_loads. grid = 128 blocks (m, bg, kq).
// P1[(m*4+kq)*64 + b][a] (no bias; summed downstream).
__global__ __launch_bounds__(256) void k1_gemm(
    const float* __restrict__ h0, const float* __restrict__ h1,
    const float* __restrict__ W1, const float* __restrict__ W2,
    const float* __restrict__ W3, const float* __restrict__ W4,
    float* __restrict__ P1) {
  int bid = blockIdx.x;            // 0..127
  int m   = bid >> 5;              // 0..3
  int bg  = (bid >> 2) & 7;        // 0..7 (8 batch rows each)
  int kq  = bid & 3;               // 0..3 (k-quarter of 256)
  const float* W = (m == 0) ? W1 : (m == 1) ? W2 : (m == 2) ? W3 : W4;
  const float* dbase = ((kq < 2) ? h0 : h1) + (kq & 1) * 256;
  const float* Wrow  = W + (size_t)(kq * 256) * A_DIM + threadIdx.x * 4;

  f32x4 acc[8];
#pragma unroll
  for (int i = 0; i < 8; ++i) acc[i] = (f32x4){0.f, 0.f, 0.f, 0.f};

#pragma unroll 2
  for (int k4 = 0; k4 < 256; k4 += 4) {
    f32x4 w0 = *reinterpret_cast<const f32x4*>(Wrow + (size_t)(k4 + 0) * A_DIM);
    f32x4 w1 = *reinterpret_cast<const f32x4*>(Wrow + (size_t)(k4 + 1) * A_DIM);
    f32x4 w2 = *reinterpret_cast<const f32x4*>(Wrow + (size_t)(k4 + 2) * A_DIM);
    f32x4 w3 = *reinterpret_cast<const f32x4*>(Wrow + (size_t)(k4 + 3) * A_DIM);
#pragma unroll
    for (int i = 0; i < 8; ++i) {
      int b = bg * 8 + i;
      f32x4 d = *reinterpret_cast<const f32x4*>(dbase + (size_t)b * H_DIM + k4);
      acc[i] += d.x * w0;
      acc[i] += d.y * w1;
      acc[i] += d.z * w2;
      acc[i] += d.w * w3;
    }
  }
#pragma unroll
  for (int i = 0; i < 8; ++i) {
    int b = bg * 8 + i;
    *reinterpret_cast<f32x4*>(
        P1 + ((size_t)(m * 4 + kq) * 64 + b) * A_DIM + threadIdx.x * 4) = acc[i];
  }
}

// K24 (fused energy + ctx-partial):
//   Phase A: df[b] = sum_kq P1 + bias (inline); e per row; p = exp(e-V)*mask
//            with fixed shift V = sum_a |v_a|; p -> LDS + p_all.
//   Phase B: P4[chunk] = sum_l p_l * outputs_row_l  (unnormalized).
__global__ __launch_bounds__(256) void k24_fused(
    const float* __restrict__ enc_features, const float* __restrict__ enc_img_features,
    const float* __restrict__ enc_outputs,  const float* __restrict__ enc_img_outputs,
    const float* __restrict__ coverage, const float* __restrict__ coverage_img,
    const float* __restrict__ enc_mask,
    const float* __restrict__ P1,
    const float* __restrict__ b1, const float* __restrict__ b2,
    const float* __restrict__ v1, const float* __restrict__ v2,
    const float* __restrict__ wc, const float* __restrict__ wci,
    const int* __restrict__ cov_set_p,
    float* __restrict__ p_all, float* __restrict__ P4) {
  __shared__ float pl[64];
  int bid  = blockIdx.x;
  int w    = threadIdx.x >> 6;
  int lane = threadIdx.x & 63;
  float covscale = (float)(*cov_set_p);
  const float *feat, *osrc, *covsrc, *P1b, *bias, *vv, *wcp, *msk;
  float* pout;
  if (bid < 1024) {
    int b = bid >> 4, chunk = bid & 15;
    int row0 = chunk * 64;
    feat   = enc_features + ((size_t)b * 1024 + row0) * 1024;
    osrc   = enc_outputs  + ((size_t)b * 1024 + row0) * 1024;
    covsrc = coverage + (size_t)b * 1024 + row0;
    msk    = enc_mask + (size_t)b * 1024 + row0;
    pout   = p_all + (size_t)b * 1024 + row0;
    P1b    = P1 + (size_t)b * 1024;            // parts 0..3 (m=0)
    bias = b1; vv = v1; wcp = wc;
  } else {
    int bi = bid - 1024;
    int b = bi >> 2, chunk = bi & 3;
    int row0 = chunk * 64;
    feat   = enc_img_features + ((size_t)b * 256 + row0) * 1024;
    osrc   = enc_img_outputs  + ((size_t)b * 256 + row0) * 1024;
    covsrc = coverage_img + (size_t)b * 256 + row0;
    msk    = nullptr;
    pout   = p_all + 65536 + (size_t)b * 256 + row0;
    P1b    = P1 + 4 * 65536 + (size_t)b * 1024; // parts 4..7 (m=1)
    bias = b2; vv = v2; wcp = wci;
  }
  // ---- Phase A ----
  f32x4 dfv[4], vvv[4], wcv[4];
#pragma unroll
  for (int p = 0; p < 4; ++p) {
    int a = p * 256 + lane * 4;
    f32x4 s = *reinterpret_cast<const f32x4*>(P1b + a);
    s += *reinterpret_cast<const f32x4*>(P1b + 65536 + a);
    s += *reinterpret_cast<const f32x4*>(P1b + 2 * 65536 + a);
    s += *reinterpret_cast<const f32x4*>(P1b + 3 * 65536 + a);
    dfv[p] = s + *reinterpret_cast<const f32x4*>(bias + a);
    vvv[p] = *reinterpret_cast<const f32x4*>(vv + a);
    wcv[p] = *reinterpret_cast<const f32x4*>(wcp + a);
  }
  // V = sum_a |v_a| : identical deterministic computation in every wave.
  float Vp = 0.f;
#pragma unroll
  for (int p = 0; p < 4; ++p)
    Vp += fabsf(vvv[p].x) + fabsf(vvv[p].y) + fabsf(vvv[p].z) + fabsf(vvv[p].w);
#pragma unroll
  for (int o = 32; o > 0; o >>= 1) Vp += __shfl_xor(Vp, o);
  float V = Vp;

#pragma unroll 2
  for (int r = 0; r < 16; ++r) {
    int row = w * 16 + r;
    float cov = covsrc[row] * covscale;
    float acc = 0.f;
#pragma unroll
    for (int p = 0; p < 4; ++p) {
      const f32x4* fp = reinterpret_cast<const f32x4*>(
          feat + (size_t)row * 1024 + p * 256 + lane * 4);
      f32x4 f = *fp;
      f32x4 x = f + dfv[p] + cov * wcv[p];
      acc += vvv[p].x * ftanh(x.x);
      acc += vvv[p].y * ftanh(x.y);
      acc += vvv[p].z * ftanh(x.z);
      acc += vvv[p].w * ftanh(x.w);
    }
#pragma unroll
    for (int o = 32; o > 0; o >>= 1) acc += __shfl_xor(acc, o);
    if (lane == 0) {
      float m = msk ? msk[row] : 1.f;
      float p = __expf(acc - V) * m;
      pl[row] = p;
      pout[row] = p;
    }
  }
  __syncthreads();
  // ---- Phase B ----
  const f32x4* srcp = reinterpret_cast<const f32x4*>(osrc) + threadIdx.x;
  f32x4 acc4 = {0.f, 0.f, 0.f, 0.f};
#pragma unroll 8
  for (int l = 0; l < 64; ++l) {
    float wt = pl[l];  // LDS broadcast
    f32x4 r = srcp[(size_t)l * 256];
    acc4 += wt * r;
  }
  *reinterpret_cast<f32x4*>(P4 + (size_t)bid * 1024 + threadIdx.x * 4) = acc4;
}

// K34 (merged norm + ctx reduce): block = batch b (64 blocks).
//   invS for text & img rows; attn/coverage outputs; ctx = invS * sum P4 chunks.
__global__ __launch_bounds__(256) void k34(
    const float* __restrict__ p_all, const float* __restrict__ P4,
    const float* __restrict__ coverage, const float* __restrict__ coverage_img,
    const int* __restrict__ cov_set_p,
    float* __restrict__ out, float* __restrict__ ctx) {
  __shared__ float redT[4], redI[4];
  int b   = blockIdx.x;
  int tid = threadIdx.x;
  float covscale = (float)(*cov_set_p);
  const float* pt = p_all + (size_t)b * 1024;
  const float* pi = p_all + 65536 + (size_t)b * 256;

  float pv[4];
  float st = 0.f;
#pragma unroll
  for (int k = 0; k < 4; ++k) {
    pv[k] = pt[k * 256 + tid];
    st += pv[k];
  }
  float piv = pi[tid];
  float si = piv;
#pragma unroll
  for (int o = 32; o > 0; o >>= 1) {
    st += __shfl_xor(st, o);
    si += __shfl_xor(si, o);
  }
  if ((tid & 63) == 0) {
    redT[tid >> 6] = st;
    redI[tid >> 6] = si;
  }
  __syncthreads();
  float invT = 1.f / (redT[0] + redT[1] + redT[2] + redT[3]);
  float invI = 1.f / (redI[0] + redI[1] + redI[2] + redI[3]);

  // attn + coverage outputs
  const float* covT = coverage + (size_t)b * 1024;
  const float* covI = coverage_img + (size_t)b * 256;
  float* attnT = out + 65536 + (size_t)b * 1024;
  float* covTo = out + 147456 + (size_t)b * 1024;
  float* attnI = out + 131072 + (size_t)b * 256;
  float* covIo = out + 212992 + (size_t)b * 256;
#pragma unroll
  for (int k = 0; k < 4; ++k) {
    int i = k * 256 + tid;
    float at = pv[k] * invT;
    attnT[i] = at;
    covTo[i] = covscale * covT[i] + at;
  }
  {
    float at = piv * invI;
    attnI[tid] = at;
    covIo[tid] = covscale * covI[tid] + at;
  }

  // ctx reduce (thread owns a-quad tid)
  f32x4 accT = {0.f, 0.f, 0.f, 0.f};
#pragma unroll
  for (int c = 0; c < 16; ++c)
    accT += *reinterpret_cast<const f32x4*>(P4 + ((size_t)(b * 16 + c)) * 1024 + tid * 4);
  *reinterpret_cast<f32x4*>(ctx + (size_t)b * 1024 + tid * 4) = accT * invT;

  f32x4 accI = {0.f, 0.f, 0.f, 0.f};
#pragma unroll
  for (int c = 0; c < 4; ++c)
    accI += *reinterpret_cast<const f32x4*>(P4 + ((size_t)(1024 + b * 4 + c)) * 1024 + tid * 4);
  *reinterpret_cast<f32x4*>(ctx + 65536 + (size_t)b * 1024 + tid * 4) = accI * invI;
}

// K5: partials of ctx_t@WA (m=0), ctx_i@WB (m=1). Same structure as K1.
__global__ __launch_bounds__(256) void k5_gemm(
    const float* __restrict__ ctx,
    const float* __restrict__ WA, const float* __restrict__ WB,
    float* __restrict__ P5) {
  int bid = blockIdx.x;            // 0..63
  int m   = bid >> 5;              // 0..1
  int bg  = (bid >> 2) & 7;
  int kq  = bid & 3;
  const float* W = m ? WB : WA;
  const float* dbase = ctx + (size_t)m * 65536 + kq * 256;
  const float* Wrow  = W + (size_t)(kq * 256) * A_DIM + threadIdx.x * 4;

  f32x4 acc[8];
#pragma unroll
  for (int i = 0; i < 8; ++i) acc[i] = (f32x4){0.f, 0.f, 0.f, 0.f};

#pragma unroll 2
  for (int k4 = 0; k4 < 256; k4 += 4) {
    f32x4 w0 = *reinterpret_cast<const f32x4*>(Wrow + (size_t)(k4 + 0) * A_DIM);
    f32x4 w1 = *reinterpret_cast<const f32x4*>(Wrow + (size_t)(k4 + 1) * A_DIM);
    f32x4 w2 = *reinterpret_cast<const f32x4*>(Wrow + (size_t)(k4 + 2) * A_DIM);
    f32x4 w3 = *reinterpret_cast<const f32x4*>(Wrow + (size_t)(k4 + 3) * A_DIM);
#pragma unroll
    for (int i = 0; i < 8; ++i) {
      int b = bg * 8 + i;
      f32x4 d = *reinterpret_cast<const f32x4*>(dbase + (size_t)b * A_DIM + k4);
      acc[i] += d.x * w0;
      acc[i] += d.y * w1;
      acc[i] += d.z * w2;
      acc[i] += d.w * w3;
    }
  }
#pragma unroll
  for (int i = 0; i < 8; ++i) {
    int b = bg * 8 + i;
    *reinterpret_cast<f32x4*>(
        P5 + ((size_t)(m * 4 + kq) * 64 + b) * A_DIM + threadIdx.x * 4) = acc[i];
  }
}

// K5b: ctx_mm = v3*tanh(g3+ctx_t@WA)*ctx_t + v4*tanh(g4+ctx_i@WB)*ctx_i
// g3/g4 summed inline from P1 parts 8..11 / 12..15 (+ bias).
__global__ __launch_bounds__(256) void k5b_final(
    const float* __restrict__ P5, const float* __restrict__ P1,
    const float* __restrict__ b3, const float* __restrict__ b4,
    const float* __restrict__ ctx,
    const float* __restrict__ v3, const float* __restrict__ v4,
    float* __restrict__ out) {
  int tid = blockIdx.x * 256 + threadIdx.x;  // 0..65535
  int a = tid & 1023;
  size_t base = tid;
  float sA = P5[base] + P5[base + 65536] + P5[base + 2 * 65536] + P5[base + 3 * 65536];
  float sB = P5[base + 4 * 65536] + P5[base + 5 * 65536] + P5[base + 6 * 65536] +
             P5[base + 7 * 65536];
  float g3v = P1[8 * 65536 + base] + P1[9 * 65536 + base] +
              P1[10 * 65536 + base] + P1[11 * 65536 + base] + b3[a];
  float g4v = P1[12 * 65536 + base] + P1[13 * 65536 + base] +
              P1[14 * 65536 + base] + P1[15 * 65536 + base] + b4[a];
  float ct = ctx[base];
  float ci = ctx[65536 + base];
  float beta1 = v3[a] * ftanh(g3v + sA);
  float beta2 = v4[a] * ftanh(g4v + sB);
  out[tid] = beta1 * ct + beta2 * ci;
}

extern "C" void kernel_launch(void* const* d_in, const int* in_sizes, int n_in,
                              void* d_out, int out_size, void* d_ws, size_t ws_size,
                              hipStream_t stream) {
  const float* h0            = (const float*)d_in[0];
  const float* h1            = (const float*)d_in[1];
  const float* enc_outputs   = (const float*)d_in[2];
  const float* enc_features  = (const float*)d_in[3];
  const float* enc_mask      = (const float*)d_in[4];
  const float* coverage      = (const float*)d_in[5];
  const float* enc_img_outs  = (const float*)d_in[6];
  const float* enc_img_feats = (const float*)d_in[7];
  // d_in[8] = img_mask (unused by reference)
  const float* coverage_img  = (const float*)d_in[9];
  const int*   cov_set       = (const int*)d_in[10];
  const float* W1 = (const float*)d_in[11];
  const float* b1 = (const float*)d_in[12];
  const float* W2 = (const float*)d_in[13];
  const float* b2 = (const float*)d_in[14];
  const float* W3 = (const float*)d_in[15];
  const float* b3 = (const float*)d_in[16];
  const float* W4 = (const float*)d_in[17];
  const float* b4 = (const float*)d_in[18];
  const float* WA = (const float*)d_in[19];
  const float* WB = (const float*)d_in[20];
  const float* v1 = (const float*)d_in[21];
  const float* v2 = (const float*)d_in[22];
  const float* v3 = (const float*)d_in[23];
  const float* v4 = (const float*)d_in[24];
  const float* wc  = (const float*)d_in[25];
  const float* wci = (const float*)d_in[26];

  float* out = (float*)d_out;
  float* ws  = (float*)d_ws;

  float* P1    = ws + WS_P1_OFF;
  float* P4    = ws + WS_P4_OFF;
  float* P5    = ws + WS_P5_OFF;   // reuses P4 region (P4 dead after k34)
  float* p_all = ws + WS_PALL_OFF;
  float* ctx   = ws + WS_CTX_OFF;

  k1_gemm<<<dim3(128), dim3(256), 0, stream>>>(h0, h1, W1, W2, W3, W4, P1);
  k24_fused<<<dim3(1280), dim3(256), 0, stream>>>(
      enc_features, enc_img_feats, enc_outputs, enc_img_outs,
      coverage, coverage_img, enc_mask, P1, b1, b2,
      v1, v2, wc, wci, cov_set, p_all, P4);
  k34<<<dim3(64), dim3(256), 0, stream>>>(p_all, P4, coverage, coverage_img,
                                          cov_set, out, ctx);
  k5_gemm<<<dim3(64), dim3(256), 0, stream>>>(ctx, WA, WB, P5);
  k5b_final<<<dim3(256), dim3(256), 0, stream>>>(P5, P1, b3, b4, ctx, v3, v4, out);
}

// Round 6
// 213.517 us; speedup vs baseline: 1.0303x; 1.0303x over previous
//
#include <hip/hip_runtime.h>
#include <cstdint>

#define A_DIM 1024
#define B_DIM 64
#define H_DIM 512

typedef float f32x4 __attribute__((ext_vector_type(4)));

// ---------------- ws layout (float offsets) ----------------
// P1  : 16 slabs * 64 * 1024 = 1,048,576  [0]
//       slab (m*4+kq) holds partials of dec@Wm (k-quarter kq).
//       k1b folds df(text) into slab 0 and dfi(img) into slab 4 (in place).
//       slabs 8..15 (g3/g4 partials) persist until k5b.
// P4  : 1280 * 1024 = 1,310,720  [1,048,576]   (ctx partials; dead after k34)
// P5  : 8 * 65536   =   524,288  [1,048,576]   (reuses P4 region)
// p_all: 65,536 + 16,384 = 81,920  [2,359,296]
// ctx : 2 * 65,536 = 131,072      [2,441,216]
// total = 2,572,288 floats ≈ 10.3 MB (same as round 5 — proven to fit)
#define WS_P1_OFF   0u
#define WS_P4_OFF   1048576u
#define WS_P5_OFF   1048576u
#define WS_PALL_OFF 2359296u
#define WS_CTX_OFF  2441216u

// d_out layout (floats): ctx_mm[0..65535], attn[65536..131071],
// attn_img[131072..147455], coverage[147456..212991], coverage_img[212992..229375]

__device__ __forceinline__ float ftanh(float x) {
  float xc = fminf(fmaxf(x, -10.f), 10.f);
  float t  = __expf(2.f * xc);
  return (t - 1.f) * __builtin_amdgcn_rcpf(t + 1.f);
}

// K1: partials of dec @ {W1..W4}. W rows loaded VECTOR-coalesced (lane = a/4),
// dec loaded as uniform sequential s_loads. grid = 128 blocks (m, bg, kq).
__global__ __launch_bounds__(256) void k1_gemm(
    const float* __restrict__ h0, const float* __restrict__ h1,
    const float* __restrict__ W1, const float* __restrict__ W2,
    const float* __restrict__ W3, const float* __restrict__ W4,
    float* __restrict__ P1) {
  int bid = blockIdx.x;            // 0..127
  int m   = bid >> 5;              // 0..3
  int bg  = (bid >> 2) & 7;        // 0..7 (8 batch rows each)
  int kq  = bid & 3;               // 0..3 (k-quarter of 256)
  const float* W = (m == 0) ? W1 : (m == 1) ? W2 : (m == 2) ? W3 : W4;
  const float* dbase = ((kq < 2) ? h0 : h1) + (kq & 1) * 256;
  const float* Wrow  = W + (size_t)(kq * 256) * A_DIM + threadIdx.x * 4;

  f32x4 acc[8];
#pragma unroll
  for (int i = 0; i < 8; ++i) acc[i] = (f32x4){0.f, 0.f, 0.f, 0.f};

#pragma unroll 2
  for (int k4 = 0; k4 < 256; k4 += 4) {
    f32x4 w0 = *reinterpret_cast<const f32x4*>(Wrow + (size_t)(k4 + 0) * A_DIM);
    f32x4 w1 = *reinterpret_cast<const f32x4*>(Wrow + (size_t)(k4 + 1) * A_DIM);
    f32x4 w2 = *reinterpret_cast<const f32x4*>(Wrow + (size_t)(k4 + 2) * A_DIM);
    f32x4 w3 = *reinterpret_cast<const f32x4*>(Wrow + (size_t)(k4 + 3) * A_DIM);
#pragma unroll
    for (int i = 0; i < 8; ++i) {
      int b = bg * 8 + i;
      f32x4 d = *reinterpret_cast<const f32x4*>(dbase + (size_t)b * H_DIM + k4);
      acc[i] += d.x * w0;
      acc[i] += d.y * w1;
      acc[i] += d.z * w2;
      acc[i] += d.w * w3;
    }
  }
#pragma unroll
  for (int i = 0; i < 8; ++i) {
    int b = bg * 8 + i;
    *reinterpret_cast<f32x4*>(
        P1 + ((size_t)(m * 4 + kq) * 64 + b) * A_DIM + threadIdx.x * 4) = acc[i];
  }
}

// K1b: fold df (m=0) and dfi (m=1) kq-partials + bias IN PLACE into slab m*4.
// Each thread reads slabs m*4+0..3 at its own offset, writes slab m*4 at the
// same offset — no cross-thread aliasing.
__global__ __launch_bounds__(256) void k1b_fold(
    float* __restrict__ P1,
    const float* __restrict__ b1, const float* __restrict__ b2) {
  int tid = blockIdx.x * 256 + threadIdx.x;  // 0..131071
  int m   = tid >> 16;                       // 0..1
  int off = tid & 65535;
  int a   = tid & 1023;
  const float* bias = m ? b2 : b1;
  size_t base = (size_t)(m * 4) * 65536 + off;
  float s = P1[base] + P1[base + 65536] + P1[base + 2 * 65536] +
            P1[base + 3 * 65536] + bias[a];
  P1[base] = s;
}

// K2: p[b,l] = exp(e - V)*mask, e = sum_a v[a]*tanh(feat + df + cov*wc),
// fixed shift V = sum_a |v_a| (deterministic, per-batch-consistent).
// 16 rows/block, 4 rows/wave; df/v/wc staged in LDS (low VGPR -> 8 waves/SIMD).
// grid: 4096 text blocks + 1024 img blocks = 5120.
__global__ __launch_bounds__(256) void k2_energy(
    const float* __restrict__ enc_features, const float* __restrict__ enc_img_features,
    const float* __restrict__ coverage, const float* __restrict__ coverage_img,
    const float* __restrict__ P1,
    const float* __restrict__ v1, const float* __restrict__ v2,
    const float* __restrict__ wc, const float* __restrict__ wci,
    const float* __restrict__ enc_mask,
    const int* __restrict__ cov_set_p,
    float* __restrict__ p_all) {
  __shared__ f32x4 sdf[256], sv[256], swc[256];
  int bid = blockIdx.x, tid = threadIdx.x;
  int w = tid >> 6, lane = tid & 63;
  float covscale = (float)(*cov_set_p);
  const float *feat, *covsrc, *dfp, *vv, *wcp, *msk;
  float* pout;
  if (bid < 4096) {
    int b = bid >> 6, row0 = (bid & 63) * 16;
    feat   = enc_features + ((size_t)b * 1024 + row0) * 1024;
    covsrc = coverage + (size_t)b * 1024 + row0;
    msk    = enc_mask + (size_t)b * 1024 + row0;
    pout   = p_all + (size_t)b * 1024 + row0;
    dfp = P1 + (size_t)b * 1024;                 // slab 0: folded df
    vv = v1; wcp = wc;
  } else {
    int bi = bid - 4096;
    int b = bi >> 4, row0 = (bi & 15) * 16;
    feat   = enc_img_features + ((size_t)b * 256 + row0) * 1024;
    covsrc = coverage_img + (size_t)b * 256 + row0;
    msk    = nullptr;
    pout   = p_all + 65536 + (size_t)b * 256 + row0;
    dfp = P1 + 4 * 65536 + (size_t)b * 1024;     // slab 4: folded dfi
    vv = v2; wcp = wci;
  }
  sdf[tid] = reinterpret_cast<const f32x4*>(dfp)[tid];
  sv[tid]  = reinterpret_cast<const f32x4*>(vv)[tid];
  swc[tid] = reinterpret_cast<const f32x4*>(wcp)[tid];
  __syncthreads();

  // V = sum_a |v_a| — identical deterministic computation in every wave.
  float Vp = 0.f;
#pragma unroll
  for (int p = 0; p < 4; ++p) {
    f32x4 t = sv[p * 64 + lane];
    Vp += fabsf(t.x) + fabsf(t.y) + fabsf(t.z) + fabsf(t.w);
  }
#pragma unroll
  for (int o = 32; o > 0; o >>= 1) Vp += __shfl_xor(Vp, o);
  float V = Vp;

#pragma unroll 2
  for (int r = 0; r < 4; ++r) {
    int row = w * 4 + r;
    float cov = covsrc[row] * covscale;
    const f32x4* frow = reinterpret_cast<const f32x4*>(feat + (size_t)row * 1024);
    float acc = 0.f;
#pragma unroll
    for (int p = 0; p < 4; ++p) {
      f32x4 f  = frow[p * 64 + lane];
      f32x4 d  = sdf[p * 64 + lane];
      f32x4 v4 = sv[p * 64 + lane];
      f32x4 w4 = swc[p * 64 + lane];
      f32x4 x = f + d + cov * w4;
      acc += v4.x * ftanh(x.x);
      acc += v4.y * ftanh(x.y);
      acc += v4.z * ftanh(x.z);
      acc += v4.w * ftanh(x.w);
    }
#pragma unroll
    for (int o = 32; o > 0; o >>= 1) acc += __shfl_xor(acc, o);
    if (lane == 0) {
      float m = msk ? msk[row] : 1.f;
      pout[row] = __expf(acc - V) * m;
    }
  }
}

// K4: ctx partials with unnormalized p. block = (b, 64-row chunk);
// 256 thr * f32x4 = one full 4KB row per iteration. Pure stream.
__global__ __launch_bounds__(256) void k4_ctx_partial(
    const float* __restrict__ enc_outputs, const float* __restrict__ enc_img_outputs,
    const float* __restrict__ p_all, float* __restrict__ P4) {
  __shared__ float pl[64];
  int bid = blockIdx.x;
  int tid = threadIdx.x;
  const float *src, *pp;
  if (bid < 1024) {
    int b = bid >> 4, c = bid & 15;
    src = enc_outputs + ((size_t)b * 1024 + c * 64) * 1024;
    pp  = p_all + (size_t)b * 1024 + c * 64;
  } else {
    int bi = bid - 1024;
    int b = bi >> 2, c = bi & 3;
    src = enc_img_outputs + ((size_t)b * 256 + c * 64) * 1024;
    pp  = p_all + 65536 + (size_t)b * 256 + c * 64;
  }
  if (tid < 64) pl[tid] = pp[tid];
  __syncthreads();
  const f32x4* srcp = reinterpret_cast<const f32x4*>(src) + tid;
  f32x4 acc = {0.f, 0.f, 0.f, 0.f};
#pragma unroll 8
  for (int l = 0; l < 64; ++l) {
    float wt = pl[l];
    f32x4 r = srcp[(size_t)l * 256];
    acc += wt * r;
  }
  *reinterpret_cast<f32x4*>(P4 + (size_t)bid * 1024 + tid * 4) = acc;
}

// K34 (norm + ctx reduce): block = batch b (64 blocks).
__global__ __launch_bounds__(256) void k34(
    const float* __restrict__ p_all, const float* __restrict__ P4,
    const float* __restrict__ coverage, const float* __restrict__ coverage_img,
    const int* __restrict__ cov_set_p,
    float* __restrict__ out, float* __restrict__ ctx) {
  __shared__ float redT[4], redI[4];
  int b   = blockIdx.x;
  int tid = threadIdx.x;
  float covscale = (float)(*cov_set_p);
  const float* pt = p_all + (size_t)b * 1024;
  const float* pi = p_all + 65536 + (size_t)b * 256;

  float pv[4];
  float st = 0.f;
#pragma unroll
  for (int k = 0; k < 4; ++k) {
    pv[k] = pt[k * 256 + tid];
    st += pv[k];
  }
  float piv = pi[tid];
  float si = piv;
#pragma unroll
  for (int o = 32; o > 0; o >>= 1) {
    st += __shfl_xor(st, o);
    si += __shfl_xor(si, o);
  }
  if ((tid & 63) == 0) {
    redT[tid >> 6] = st;
    redI[tid >> 6] = si;
  }
  __syncthreads();
  float invT = 1.f / (redT[0] + redT[1] + redT[2] + redT[3]);
  float invI = 1.f / (redI[0] + redI[1] + redI[2] + redI[3]);

  const float* covT = coverage + (size_t)b * 1024;
  const float* covI = coverage_img + (size_t)b * 256;
  float* attnT = out + 65536 + (size_t)b * 1024;
  float* covTo = out + 147456 + (size_t)b * 1024;
  float* attnI = out + 131072 + (size_t)b * 256;
  float* covIo = out + 212992 + (size_t)b * 256;
#pragma unroll
  for (int k = 0; k < 4; ++k) {
    int i = k * 256 + tid;
    float at = pv[k] * invT;
    attnT[i] = at;
    covTo[i] = covscale * covT[i] + at;
  }
  {
    float at = piv * invI;
    attnI[tid] = at;
    covIo[tid] = covscale * covI[tid] + at;
  }

  f32x4 accT = {0.f, 0.f, 0.f, 0.f};
#pragma unroll
  for (int c = 0; c < 16; ++c)
    accT += *reinterpret_cast<const f32x4*>(P4 + ((size_t)(b * 16 + c)) * 1024 + tid * 4);
  *reinterpret_cast<f32x4*>(ctx + (size_t)b * 1024 + tid * 4) = accT * invT;

  f32x4 accI = {0.f, 0.f, 0.f, 0.f};
#pragma unroll
  for (int c = 0; c < 4; ++c)
    accI += *reinterpret_cast<const f32x4*>(P4 + ((size_t)(1024 + b * 4 + c)) * 1024 + tid * 4);
  *reinterpret_cast<f32x4*>(ctx + 65536 + (size_t)b * 1024 + tid * 4) = accI * invI;
}

// K5: partials of ctx_t@WA (m=0), ctx_i@WB (m=1). Same structure as K1.
__global__ __launch_bounds__(256) void k5_gemm(
    const float* __restrict__ ctx,
    const float* __restrict__ WA, const float* __restrict__ WB,
    float* __restrict__ P5) {
  int bid = blockIdx.x;            // 0..63
  int m   = bid >> 5;              // 0..1
  int bg  = (bid >> 2) & 7;
  int kq  = bid & 3;
  const float* W = m ? WB : WA;
  const float* dbase = ctx + (size_t)m * 65536 + kq * 256;
  const float* Wrow  = W + (size_t)(kq * 256) * A_DIM + threadIdx.x * 4;

  f32x4 acc[8];
#pragma unroll
  for (int i = 0; i < 8; ++i) acc[i] = (f32x4){0.f, 0.f, 0.f, 0.f};

#pragma unroll 2
  for (int k4 = 0; k4 < 256; k4 += 4) {
    f32x4 w0 = *reinterpret_cast<const f32x4*>(Wrow + (size_t)(k4 + 0) * A_DIM);
    f32x4 w1 = *reinterpret_cast<const f32x4*>(Wrow + (size_t)(k4 + 1) * A_DIM);
    f32x4 w2 = *reinterpret_cast<const f32x4*>(Wrow + (size_t)(k4 + 2) * A_DIM);
    f32x4 w3 = *reinterpret_cast<const f32x4*>(Wrow + (size_t)(k4 + 3) * A_DIM);
#pragma unroll
    for (int i = 0; i < 8; ++i) {
      int b = bg * 8 + i;
      f32x4 d = *reinterpret_cast<const f32x4*>(dbase + (size_t)b * A_DIM + k4);
      acc[i] += d.x * w0;
      acc[i] += d.y * w1;
      acc[i] += d.z * w2;
      acc[i] += d.w * w3;
    }
  }
#pragma unroll
  for (int i = 0; i < 8; ++i) {
    int b = bg * 8 + i;
    *reinterpret_cast<f32x4*>(
        P5 + ((size_t)(m * 4 + kq) * 64 + b) * A_DIM + threadIdx.x * 4) = acc[i];
  }
}

// K5b: ctx_mm = v3*tanh(g3+ctx_t@WA)*ctx_t + v4*tanh(g4+ctx_i@WB)*ctx_i
// g3/g4 summed inline from P1 slabs 8..11 / 12..15 (+ bias).
__global__ __launch_bounds__(256) void k5b_final(
    const float* __restrict__ P5, const float* __restrict__ P1,
    const float* __restrict__ b3, const float* __restrict__ b4,
    const float* __restrict__ ctx,
    const float* __restrict__ v3, const float* __restrict__ v4,
    float* __restrict__ out) {
  int tid = blockIdx.x * 256 + threadIdx.x;  // 0..65535
  int a = tid & 1023;
  size_t base = tid;
  float sA = P5[base] + P5[base + 65536] + P5[base + 2 * 65536] + P5[base + 3 * 65536];
  float sB = P5[base + 4 * 65536] + P5[base + 5 * 65536] + P5[base + 6 * 65536] +
             P5[base + 7 * 65536];
  float g3v = P1[8 * 65536 + base] + P1[9 * 65536 + base] +
              P1[10 * 65536 + base] + P1[11 * 65536 + base] + b3[a];
  float g4v = P1[12 * 65536 + base] + P1[13 * 65536 + base] +
              P1[14 * 65536 + base] + P1[15 * 65536 + base] + b4[a];
  float ct = ctx[base];
  float ci = ctx[65536 + base];
  float beta1 = v3[a] * ftanh(g3v + sA);
  float beta2 = v4[a] * ftanh(g4v + sB);
  out[tid] = beta1 * ct + beta2 * ci;
}

extern "C" void kernel_launch(void* const* d_in, const int* in_sizes, int n_in,
                              void* d_out, int out_size, void* d_ws, size_t ws_size,
                              hipStream_t stream) {
  const float* h0            = (const float*)d_in[0];
  const float* h1            = (const float*)d_in[1];
  const float* enc_outputs   = (const float*)d_in[2];
  const float* enc_features  = (const float*)d_in[3];
  const float* enc_mask      = (const float*)d_in[4];
  const float* coverage      = (const float*)d_in[5];
  const float* enc_img_outs  = (const float*)d_in[6];
  const float* enc_img_feats = (const float*)d_in[7];
  // d_in[8] = img_mask (unused by reference)
  const float* coverage_img  = (const float*)d_in[9];
  const int*   cov_set       = (const int*)d_in[10];
  const float* W1 = (const float*)d_in[11];
  const float* b1 = (const float*)d_in[12];
  const float* W2 = (const float*)d_in[13];
  const float* b2 = (const float*)d_in[14];
  const float* W3 = (const float*)d_in[15];
  const float* b3 = (const float*)d_in[16];
  const float* W4 = (const float*)d_in[17];
  const float* b4 = (const float*)d_in[18];
  const float* WA = (const float*)d_in[19];
  const float* WB = (const float*)d_in[20];
  const float* v1 = (const float*)d_in[21];
  const float* v2 = (const float*)d_in[22];
  const float* v3 = (const float*)d_in[23];
  const float* v4 = (const float*)d_in[24];
  const float* wc  = (const float*)d_in[25];
  const float* wci = (const float*)d_in[26];

  float* out = (float*)d_out;
  float* ws  = (float*)d_ws;

  float* P1    = ws + WS_P1_OFF;
  float* P4    = ws + WS_P4_OFF;
  float* P5    = ws + WS_P5_OFF;   // reuses P4 region (P4 dead after k34)
  float* p_all = ws + WS_PALL_OFF;
  float* ctx   = ws + WS_CTX_OFF;

  k1_gemm<<<dim3(128), dim3(256), 0, stream>>>(h0, h1, W1, W2, W3, W4, P1);
  k1b_fold<<<dim3(512), dim3(256), 0, stream>>>(P1, b1, b2);
  k2_energy<<<dim3(5120), dim3(256), 0, stream>>>(
      enc_features, enc_img_feats, coverage, coverage_img, P1,
      v1, v2, wc, wci, enc_mask, cov_set, p_all);
  k4_ctx_partial<<<dim3(1280), dim3(256), 0, stream>>>(enc_outputs, enc_img_outs,
                                                       p_all, P4);
  k34<<<dim3(64), dim3(256), 0, stream>>>(p_all, P4, coverage, coverage_img,
                                          cov_set, out, ctx);
  k5_gemm<<<dim3(64), dim3(256), 0, stream>>>(ctx, WA, WB, P5);
  k5b_final<<<dim3(256), dim3(256), 0, stream>>>(P5, P1, b3, b4, ctx, v3, v4, out);
}

// Round 7
// 197.052 us; speedup vs baseline: 1.1164x; 1.0836x over previous
//
#include <hip/hip_runtime.h>
#include <cstdint>

#define A_DIM 1024
#define B_DIM 64
#define H_DIM 512

typedef float f32x4 __attribute__((ext_vector_type(4)));

// ---------------- ws layout (float offsets) ----------------
// P1  : 16 slabs * 64 * 1024 = 1,048,576  [0]
//       k1b folds df(text) into slab 0, dfi(img) into slab 4 (in place).
//       slabs 8..15 (g3/g4 partials) persist until k5b.
// P4  : 1280 * 1024 = 1,310,720  [1,048,576]   (ctx partials; dead after k34)
// P5  : 8 * 65536   =   524,288  [1,048,576]   (reuses P4 region)
// p_all: 65,536 + 16,384 = 81,920  [2,359,296]
// ctx : 2 * 65,536 = 131,072      [2,441,216]
// total = 2,572,288 floats ≈ 10.3 MB (unchanged from rounds 5/6 — fits)
#define WS_P1_OFF   0u
#define WS_P4_OFF   1048576u
#define WS_P5_OFF   1048576u
#define WS_PALL_OFF 2359296u
#define WS_CTX_OFF  2441216u

// d_out layout (floats): ctx_mm[0..65535], attn[65536..131071],
// attn_img[131072..147455], coverage[147456..212991], coverage_img[212992..229375]

__device__ __forceinline__ float ftanh(float x) {
  float xc = fminf(fmaxf(x, -10.f), 10.f);
  float t  = __expf(2.f * xc);
  return (t - 1.f) * __builtin_amdgcn_rcpf(t + 1.f);
}

// K1: partials of dec @ {W1..W4}. W rows loaded VECTOR-coalesced (lane = a/4),
// dec loaded as uniform sequential s_loads. grid = 128 blocks (m, bg, kq).
__global__ __launch_bounds__(256) void k1_gemm(
    const float* __restrict__ h0, const float* __restrict__ h1,
    const float* __restrict__ W1, const float* __restrict__ W2,
    const float* __restrict__ W3, const float* __restrict__ W4,
    float* __restrict__ P1) {
  int bid = blockIdx.x;            // 0..127
  int m   = bid >> 5;              // 0..3
  int bg  = (bid >> 2) & 7;        // 0..7 (8 batch rows each)
  int kq  = bid & 3;               // 0..3 (k-quarter of 256)
  const float* W = (m == 0) ? W1 : (m == 1) ? W2 : (m == 2) ? W3 : W4;
  const float* dbase = ((kq < 2) ? h0 : h1) + (kq & 1) * 256;
  const float* Wrow  = W + (size_t)(kq * 256) * A_DIM + threadIdx.x * 4;

  f32x4 acc[8];
#pragma unroll
  for (int i = 0; i < 8; ++i) acc[i] = (f32x4){0.f, 0.f, 0.f, 0.f};

#pragma unroll 2
  for (int k4 = 0; k4 < 256; k4 += 4) {
    f32x4 w0 = *reinterpret_cast<const f32x4*>(Wrow + (size_t)(k4 + 0) * A_DIM);
    f32x4 w1 = *reinterpret_cast<const f32x4*>(Wrow + (size_t)(k4 + 1) * A_DIM);
    f32x4 w2 = *reinterpret_cast<const f32x4*>(Wrow + (size_t)(k4 + 2) * A_DIM);
    f32x4 w3 = *reinterpret_cast<const f32x4*>(Wrow + (size_t)(k4 + 3) * A_DIM);
#pragma unroll
    for (int i = 0; i < 8; ++i) {
      int b = bg * 8 + i;
      f32x4 d = *reinterpret_cast<const f32x4*>(dbase + (size_t)b * H_DIM + k4);
      acc[i] += d.x * w0;
      acc[i] += d.y * w1;
      acc[i] += d.z * w2;
      acc[i] += d.w * w3;
    }
  }
#pragma unroll
  for (int i = 0; i < 8; ++i) {
    int b = bg * 8 + i;
    *reinterpret_cast<f32x4*>(
        P1 + ((size_t)(m * 4 + kq) * 64 + b) * A_DIM + threadIdx.x * 4) = acc[i];
  }
}

// K1b: fold df (m=0) and dfi (m=1) kq-partials + bias IN PLACE into slab m*4.
__global__ __launch_bounds__(256) void k1b_fold(
    float* __restrict__ P1,
    const float* __restrict__ b1, const float* __restrict__ b2) {
  int tid = blockIdx.x * 256 + threadIdx.x;  // 0..131071
  int m   = tid >> 16;                       // 0..1
  int off = tid & 65535;
  int a   = tid & 1023;
  const float* bias = m ? b2 : b1;
  size_t base = (size_t)(m * 4) * 65536 + off;
  float s = P1[base] + P1[base + 65536] + P1[base + 2 * 65536] +
            P1[base + 3 * 65536] + bias[a];
  P1[base] = s;
}

// K24 (fused energy + ctx partial), 512 threads = 8 waves, 64-row chunk/block.
//   Phase A: wave w computes p = exp(e-V)*mask for rows w*8..w*8+7 with an
//            explicit 2-row register ping-pong on the feat stream (nt loads).
//   Phase B: the whole block streams its 64 output rows (2 rows/iteration,
//            4-deep register rotation, nt) accumulating P4[bid] = sum p_l*row_l.
// grid: 1024 text + 256 img = 1280 blocks -> 10240 waves (occupancy cap).
__global__ __launch_bounds__(512, 8) void k24_fused(
    const float* __restrict__ enc_features, const float* __restrict__ enc_img_features,
    const float* __restrict__ enc_outputs,  const float* __restrict__ enc_img_outputs,
    const float* __restrict__ coverage, const float* __restrict__ coverage_img,
    const float* __restrict__ enc_mask,
    const float* __restrict__ P1,
    const float* __restrict__ v1, const float* __restrict__ v2,
    const float* __restrict__ wc, const float* __restrict__ wci,
    const int* __restrict__ cov_set_p,
    float* __restrict__ p_all, float* __restrict__ P4) {
  __shared__ f32x4 sdf[256], sv[256], swc[256];
  __shared__ f32x4 sacc[256];
  __shared__ float pl[64];
  int bid = blockIdx.x, tid = threadIdx.x;
  int w = tid >> 6, lane = tid & 63;
  float covscale = (float)(*cov_set_p);
  const float *feat, *osrc, *covsrc, *dfp, *vv, *wcp, *msk;
  float* pout;
  if (bid < 1024) {
    int b = bid >> 4, row0b = (bid & 15) * 64;
    feat   = enc_features + ((size_t)b * 1024 + row0b) * 1024;
    osrc   = enc_outputs  + ((size_t)b * 1024 + row0b) * 1024;
    covsrc = coverage + (size_t)b * 1024 + row0b;
    msk    = enc_mask + (size_t)b * 1024 + row0b;
    pout   = p_all + (size_t)b * 1024 + row0b;
    dfp = P1 + (size_t)b * 1024;                 // slab 0: folded df
    vv = v1; wcp = wc;
  } else {
    int bi = bid - 1024;
    int b = bi >> 2, row0b = (bi & 3) * 64;
    feat   = enc_img_features + ((size_t)b * 256 + row0b) * 1024;
    osrc   = enc_img_outputs  + ((size_t)b * 256 + row0b) * 1024;
    covsrc = coverage_img + (size_t)b * 256 + row0b;
    msk    = nullptr;
    pout   = p_all + 65536 + (size_t)b * 256 + row0b;
    dfp = P1 + 4 * 65536 + (size_t)b * 1024;     // slab 4: folded dfi
    vv = v2; wcp = wci;
  }
  // stage operands: threads 0..255 -> sdf, 256..511 -> sv+swc
  if (tid < 256) {
    sdf[tid] = reinterpret_cast<const f32x4*>(dfp)[tid];
  } else {
    int t = tid - 256;
    sv[t]  = reinterpret_cast<const f32x4*>(vv)[t];
    swc[t] = reinterpret_cast<const f32x4*>(wcp)[t];
  }
  __syncthreads();

  // ---- Phase A: 8 rows per wave ----
  int row0 = w * 8;
  // one lane-spread load for cov and mask of this wave's 8 rows
  float covv = (lane < 8) ? covsrc[row0 + lane] : 0.f;
  float mskv = (lane < 8) ? (msk ? msk[row0 + lane] : 1.f) : 1.f;

  // V = sum_a |v_a| (deterministic, identical in every wave)
  float Vp = 0.f;
#pragma unroll
  for (int p = 0; p < 4; ++p) {
    f32x4 t = sv[p * 64 + lane];
    Vp += fabsf(t.x) + fabsf(t.y) + fabsf(t.z) + fabsf(t.w);
  }
#pragma unroll
  for (int o = 32; o > 0; o >>= 1) Vp += __shfl_xor(Vp, o);
  float V = Vp;

  const f32x4* F = reinterpret_cast<const f32x4*>(feat);
  f32x4 cur[4], nxt[4];
#pragma unroll
  for (int p = 0; p < 4; ++p)
    cur[p] = __builtin_nontemporal_load(&F[(size_t)row0 * 256 + p * 64 + lane]);

#pragma unroll
  for (int r = 0; r < 8; ++r) {
    int row = row0 + r;
    if (r < 7) {
#pragma unroll
      for (int p = 0; p < 4; ++p)
        nxt[p] = __builtin_nontemporal_load(&F[(size_t)(row + 1) * 256 + p * 64 + lane]);
    }
    float crow = __shfl(covv, r) * covscale;
    float mrow = __shfl(mskv, r);
    float acc = 0.f;
#pragma unroll
    for (int p = 0; p < 4; ++p) {
      f32x4 d  = sdf[p * 64 + lane];
      f32x4 v4 = sv[p * 64 + lane];
      f32x4 w4 = swc[p * 64 + lane];
      f32x4 x = cur[p] + d + crow * w4;
      acc += v4.x * ftanh(x.x);
      acc += v4.y * ftanh(x.y);
      acc += v4.z * ftanh(x.z);
      acc += v4.w * ftanh(x.w);
    }
#pragma unroll
    for (int o = 32; o > 0; o >>= 1) acc += __shfl_xor(acc, o);
    if (lane == 0) {
      float p = __expf(acc - V) * mrow;
      pl[row] = p;
      pout[row] = p;
    }
#pragma unroll
    for (int p = 0; p < 4; ++p) cur[p] = nxt[p];
  }
  __syncthreads();

  // ---- Phase B: 2 rows/iteration across the block, 4-deep rotation ----
  int g  = tid >> 8;        // 0 or 1 (row parity)
  int aq = tid & 255;       // a-quad
  const f32x4* O = reinterpret_cast<const f32x4*>(osrc) + aq;
  // this half handles rows g, g+2, ..., g+62 (32 rows)
  f32x4 buf[4];
#pragma unroll
  for (int j = 0; j < 4; ++j)
    buf[j] = __builtin_nontemporal_load(&O[(size_t)(g + 2 * j) * 256]);
  f32x4 acc4 = {0.f, 0.f, 0.f, 0.f};
#pragma unroll 1
  for (int l = 0; l < 32; l += 4) {
    f32x4 b0 = buf[0], b1 = buf[1], b2 = buf[2], b3 = buf[3];
    if (l + 4 < 32) {
#pragma unroll
      for (int j = 0; j < 4; ++j)
        buf[j] = __builtin_nontemporal_load(&O[(size_t)(g + 2 * (l + 4 + j)) * 256]);
    }
    acc4 += pl[g + 2 * (l + 0)] * b0;
    acc4 += pl[g + 2 * (l + 1)] * b1;
    acc4 += pl[g + 2 * (l + 2)] * b2;
    acc4 += pl[g + 2 * (l + 3)] * b3;
  }
  if (g == 1) sacc[aq] = acc4;
  __syncthreads();
  if (g == 0) {
    acc4 += sacc[aq];
    *reinterpret_cast<f32x4*>(P4 + (size_t)bid * 1024 + aq * 4) = acc4;
  }
}

// K34 (norm + ctx reduce): block = batch b (64 blocks).
__global__ __launch_bounds__(256) void k34(
    const float* __restrict__ p_all, const float* __restrict__ P4,
    const float* __restrict__ coverage, const float* __restrict__ coverage_img,
    const int* __restrict__ cov_set_p,
    float* __restrict__ out, float* __restrict__ ctx) {
  __shared__ float redT[4], redI[4];
  int b   = blockIdx.x;
  int tid = threadIdx.x;
  float covscale = (float)(*cov_set_p);
  const float* pt = p_all + (size_t)b * 1024;
  const float* pi = p_all + 65536 + (size_t)b * 256;

  float pv[4];
  float st = 0.f;
#pragma unroll
  for (int k = 0; k < 4; ++k) {
    pv[k] = pt[k * 256 + tid];
    st += pv[k];
  }
  float piv = pi[tid];
  float si = piv;
#pragma unroll
  for (int o = 32; o > 0; o >>= 1) {
    st += __shfl_xor(st, o);
    si += __shfl_xor(si, o);
  }
  if ((tid & 63) == 0) {
    redT[tid >> 6] = st;
    redI[tid >> 6] = si;
  }
  __syncthreads();
  float invT = 1.f / (redT[0] + redT[1] + redT[2] + redT[3]);
  float invI = 1.f / (redI[0] + redI[1] + redI[2] + redI[3]);

  const float* covT = coverage + (size_t)b * 1024;
  const float* covI = coverage_img + (size_t)b * 256;
  float* attnT = out + 65536 + (size_t)b * 1024;
  float* covTo = out + 147456 + (size_t)b * 1024;
  float* attnI = out + 131072 + (size_t)b * 256;
  float* covIo = out + 212992 + (size_t)b * 256;
#pragma unroll
  for (int k = 0; k < 4; ++k) {
    int i = k * 256 + tid;
    float at = pv[k] * invT;
    attnT[i] = at;
    covTo[i] = covscale * covT[i] + at;
  }
  {
    float at = piv * invI;
    attnI[tid] = at;
    covIo[tid] = covscale * covI[tid] + at;
  }

  f32x4 accT = {0.f, 0.f, 0.f, 0.f};
#pragma unroll
  for (int c = 0; c < 16; ++c)
    accT += *reinterpret_cast<const f32x4*>(P4 + ((size_t)(b * 16 + c)) * 1024 + tid * 4);
  *reinterpret_cast<f32x4*>(ctx + (size_t)b * 1024 + tid * 4) = accT * invT;

  f32x4 accI = {0.f, 0.f, 0.f, 0.f};
#pragma unroll
  for (int c = 0; c < 4; ++c)
    accI += *reinterpret_cast<const f32x4*>(P4 + ((size_t)(1024 + b * 4 + c)) * 1024 + tid * 4);
  *reinterpret_cast<f32x4*>(ctx + 65536 + (size_t)b * 1024 + tid * 4) = accI * invI;
}

// K5: partials of ctx_t@WA (m=0), ctx_i@WB (m=1). Same structure as K1.
__global__ __launch_bounds__(256) void k5_gemm(
    const float* __restrict__ ctx,
    const float* __restrict__ WA, const float* __restrict__ WB,
    float* __restrict__ P5) {
  int bid = blockIdx.x;            // 0..63
  int m   = bid >> 5;              // 0..1
  int bg  = (bid >> 2) & 7;
  int kq  = bid & 3;
  const float* W = m ? WB : WA;
  const float* dbase = ctx + (size_t)m * 65536 + kq * 256;
  const float* Wrow  = W + (size_t)(kq * 256) * A_DIM + threadIdx.x * 4;

  f32x4 acc[8];
#pragma unroll
  for (int i = 0; i < 8; ++i) acc[i] = (f32x4){0.f, 0.f, 0.f, 0.f};

#pragma unroll 2
  for (int k4 = 0; k4 < 256; k4 += 4) {
    f32x4 w0 = *reinterpret_cast<const f32x4*>(Wrow + (size_t)(k4 + 0) * A_DIM);
    f32x4 w1 = *reinterpret_cast<const f32x4*>(Wrow + (size_t)(k4 + 1) * A_DIM);
    f32x4 w2 = *reinterpret_cast<const f32x4*>(Wrow + (size_t)(k4 + 2) * A_DIM);
    f32x4 w3 = *reinterpret_cast<const f32x4*>(Wrow + (size_t)(k4 + 3) * A_DIM);
#pragma unroll
    for (int i = 0; i < 8; ++i) {
      int b = bg * 8 + i;
      f32x4 d = *reinterpret_cast<const f32x4*>(dbase + (size_t)b * A_DIM + k4);
      acc[i] += d.x * w0;
      acc[i] += d.y * w1;
      acc[i] += d.z * w2;
      acc[i] += d.w * w3;
    }
  }
#pragma unroll
  for (int i = 0; i < 8; ++i) {
    int b = bg * 8 + i;
    *reinterpret_cast<f32x4*>(
        P5 + ((size_t)(m * 4 + kq) * 64 + b) * A_DIM + threadIdx.x * 4) = acc[i];
  }
}

// K5b: ctx_mm = v3*tanh(g3+ctx_t@WA)*ctx_t + v4*tanh(g4+ctx_i@WB)*ctx_i
__global__ __launch_bounds__(256) void k5b_final(
    const float* __restrict__ P5, const float* __restrict__ P1,
    const float* __restrict__ b3, const float* __restrict__ b4,
    const float* __restrict__ ctx,
    const float* __restrict__ v3, const float* __restrict__ v4,
    float* __restrict__ out) {
  int tid = blockIdx.x * 256 + threadIdx.x;  // 0..65535
  int a = tid & 1023;
  size_t base = tid;
  float sA = P5[base] + P5[base + 65536] + P5[base + 2 * 65536] + P5[base + 3 * 65536];
  float sB = P5[base + 4 * 65536] + P5[base + 5 * 65536] + P5[base + 6 * 65536] +
             P5[base + 7 * 65536];
  float g3v = P1[8 * 65536 + base] + P1[9 * 65536 + base] +
              P1[10 * 65536 + base] + P1[11 * 65536 + base] + b3[a];
  float g4v = P1[12 * 65536 + base] + P1[13 * 65536 + base] +
              P1[14 * 65536 + base] + P1[15 * 65536 + base] + b4[a];
  float ct = ctx[base];
  float ci = ctx[65536 + base];
  float beta1 = v3[a] * ftanh(g3v + sA);
  float beta2 = v4[a] * ftanh(g4v + sB);
  out[tid] = beta1 * ct + beta2 * ci;
}

extern "C" void kernel_launch(void* const* d_in, const int* in_sizes, int n_in,
                              void* d_out, int out_size, void* d_ws, size_t ws_size,
                              hipStream_t stream) {
  const float* h0            = (const float*)d_in[0];
  const float* h1            = (const float*)d_in[1];
  const float* enc_outputs   = (const float*)d_in[2];
  const float* enc_features  = (const float*)d_in[3];
  const float* enc_mask      = (const float*)d_in[4];
  const float* coverage      = (const float*)d_in[5];
  const float* enc_img_outs  = (const float*)d_in[6];
  const float* enc_img_feats = (const float*)d_in[7];
  // d_in[8] = img_mask (unused by reference)
  const float* coverage_img  = (const float*)d_in[9];
  const int*   cov_set       = (const int*)d_in[10];
  const float* W1 = (const float*)d_in[11];
  const float* b1 = (const float*)d_in[12];
  const float* W2 = (const float*)d_in[13];
  const float* b2 = (const float*)d_in[14];
  const float* W3 = (const float*)d_in[15];
  const float* b3 = (const float*)d_in[16];
  const float* W4 = (const float*)d_in[17];
  const float* b4 = (const float*)d_in[18];
  const float* WA = (const float*)d_in[19];
  const float* WB = (const float*)d_in[20];
  const float* v1 = (const float*)d_in[21];
  const float* v2 = (const float*)d_in[22];
  const float* v3 = (const float*)d_in[23];
  const float* v4 = (const float*)d_in[24];
  const float* wc  = (const float*)d_in[25];
  const float* wci = (const float*)d_in[26];

  float* out = (float*)d_out;
  float* ws  = (float*)d_ws;

  float* P1    = ws + WS_P1_OFF;
  float* P4    = ws + WS_P4_OFF;
  float* P5    = ws + WS_P5_OFF;   // reuses P4 region (P4 dead after k34)
  float* p_all = ws + WS_PALL_OFF;
  float* ctx   = ws + WS_CTX_OFF;

  k1_gemm<<<dim3(128), dim3(256), 0, stream>>>(h0, h1, W1, W2, W3, W4, P1);
  k1b_fold<<<dim3(512), dim3(256), 0, stream>>>(P1, b1, b2);
  k24_fused<<<dim3(1280), dim3(512), 0, stream>>>(
      enc_features, enc_img_feats, enc_outputs, enc_img_outs,
      coverage, coverage_img, enc_mask, P1,
      v1, v2, wc, wci, cov_set, p_all, P4);
  k34<<<dim3(64), dim3(256), 0, stream>>>(p_all, P4, coverage, coverage_img,
                                          cov_set, out, ctx);
  k5_gemm<<<dim3(64), dim3(256), 0, stream>>>(ctx, WA, WB, P5);
  k5b_final<<<dim3(256), dim3(256), 0, stream>>>(P5, P1, b3, b4, ctx, v3, v4, out);
}

// Round 8
// 180.630 us; speedup vs baseline: 1.2179x; 1.0909x over previous
//
#include <hip/hip_runtime.h>
#include <cstdint>

#define A_DIM 1024
#define B_DIM 64
#define H_DIM 512

typedef float f32x4 __attribute__((ext_vector_type(4)));

// ---------------- ws layout (float offsets) ----------------
// P1  : 16 slabs * 64 * 1024 = 1,048,576  [0]
//       k1b folds df(text) into slab 0, dfi(img) into slab 4 (in place).
//       slabs 8..15 (g3/g4 partials) persist until k5b.
// P4  : 1280 * 1024 = 1,310,720  [1,048,576]   (ctx partials; dead after k34)
// P5  : 8 * 65536   =   524,288  [1,048,576]   (reuses P4 region)
// p_all: 65,536 + 16,384 = 81,920  [2,359,296]
// ctx : 2 * 65,536 = 131,072      [2,441,216]
#define WS_P1_OFF   0u
#define WS_P4_OFF   1048576u
#define WS_P5_OFF   1048576u
#define WS_PALL_OFF 2359296u
#define WS_CTX_OFF  2441216u

// d_out layout (floats): ctx_mm[0..65535], attn[65536..131071],
// attn_img[131072..147455], coverage[147456..212991], coverage_img[212992..229375]

__device__ __forceinline__ float ftanh(float x) {
  float xc = fminf(fmaxf(x, -10.f), 10.f);
  float t  = __expf(2.f * xc);
  return (t - 1.f) * __builtin_amdgcn_rcpf(t + 1.f);
}

// K1: partials of dec @ {W1..W4}. W rows VECTOR-coalesced (lane = a/4), dec
// uniform s_loads. grid = 256 blocks (m x 16 bg x 4 kq), 4 batch rows each.
__global__ __launch_bounds__(256) void k1_gemm(
    const float* __restrict__ h0, const float* __restrict__ h1,
    const float* __restrict__ W1, const float* __restrict__ W2,
    const float* __restrict__ W3, const float* __restrict__ W4,
    float* __restrict__ P1) {
  int bid = blockIdx.x;            // 0..255
  int m   = bid >> 6;              // 0..3
  int bg  = (bid >> 2) & 15;       // 0..15 (4 batch rows each)
  int kq  = bid & 3;               // 0..3 (k-quarter of 256)
  const float* W = (m == 0) ? W1 : (m == 1) ? W2 : (m == 2) ? W3 : W4;
  const float* dbase = ((kq < 2) ? h0 : h1) + (kq & 1) * 256;
  const float* Wrow  = W + (size_t)(kq * 256) * A_DIM + threadIdx.x * 4;

  f32x4 acc[4];
#pragma unroll
  for (int i = 0; i < 4; ++i) acc[i] = (f32x4){0.f, 0.f, 0.f, 0.f};

#pragma unroll 2
  for (int k4 = 0; k4 < 256; k4 += 4) {
    f32x4 w0 = *reinterpret_cast<const f32x4*>(Wrow + (size_t)(k4 + 0) * A_DIM);
    f32x4 w1 = *reinterpret_cast<const f32x4*>(Wrow + (size_t)(k4 + 1) * A_DIM);
    f32x4 w2 = *reinterpret_cast<const f32x4*>(Wrow + (size_t)(k4 + 2) * A_DIM);
    f32x4 w3 = *reinterpret_cast<const f32x4*>(Wrow + (size_t)(k4 + 3) * A_DIM);
#pragma unroll
    for (int i = 0; i < 4; ++i) {
      int b = bg * 4 + i;
      f32x4 d = *reinterpret_cast<const f32x4*>(dbase + (size_t)b * H_DIM + k4);
      acc[i] += d.x * w0;
      acc[i] += d.y * w1;
      acc[i] += d.z * w2;
      acc[i] += d.w * w3;
    }
  }
#pragma unroll
  for (int i = 0; i < 4; ++i) {
    int b = bg * 4 + i;
    *reinterpret_cast<f32x4*>(
        P1 + ((size_t)(m * 4 + kq) * 64 + b) * A_DIM + threadIdx.x * 4) = acc[i];
  }
}

// K1b: fold df (m=0) and dfi (m=1) kq-partials + bias IN PLACE into slab m*4.
__global__ __launch_bounds__(256) void k1b_fold(
    float* __restrict__ P1,
    const float* __restrict__ b1, const float* __restrict__ b2) {
  int tid = blockIdx.x * 256 + threadIdx.x;  // 0..131071
  int m   = tid >> 16;                       // 0..1
  int off = tid & 65535;
  int a   = tid & 1023;
  const float* bias = m ? b2 : b1;
  size_t base = (size_t)(m * 4) * 65536 + off;
  float s = P1[base] + P1[base + 65536] + P1[base + 2 * 65536] +
            P1[base + 3 * 65536] + bias[a];
  P1[base] = s;
}

// K24: fused energy + ctx partial, SUBTILE-INTERLEAVED.
// 512 threads = 8 waves; 64-row chunk = 4 subtiles of 16 rows.
// Per subtile: A (2 rows/wave, 8KB loads up front) -> barrier ->
//              B (8-deep rotation over the 16 output rows, 8KB/wave).
// Streams feat and outputs CONCURRENTLY at 64KB granularity chip-wide.
__global__ __launch_bounds__(512) void k24_fused(
    const float* __restrict__ enc_features, const float* __restrict__ enc_img_features,
    const float* __restrict__ enc_outputs,  const float* __restrict__ enc_img_outputs,
    const float* __restrict__ coverage, const float* __restrict__ coverage_img,
    const float* __restrict__ enc_mask,
    const float* __restrict__ P1,
    const float* __restrict__ v1, const float* __restrict__ v2,
    const float* __restrict__ wc, const float* __restrict__ wci,
    const int* __restrict__ cov_set_p,
    float* __restrict__ p_all, float* __restrict__ P4) {
  __shared__ f32x4 sdf[256], sv[256], swc[256];
  __shared__ f32x4 sacc[256];
  __shared__ float pl[64];
  int bid = blockIdx.x, tid = threadIdx.x;
  int w = tid >> 6, lane = tid & 63;
  float covscale = (float)(*cov_set_p);
  const float *feat, *osrc, *covsrc, *dfp, *vv, *wcp, *msk;
  float* pout;
  if (bid < 1024) {
    int b = bid >> 4, row0b = (bid & 15) * 64;
    feat   = enc_features + ((size_t)b * 1024 + row0b) * 1024;
    osrc   = enc_outputs  + ((size_t)b * 1024 + row0b) * 1024;
    covsrc = coverage + (size_t)b * 1024 + row0b;
    msk    = enc_mask + (size_t)b * 1024 + row0b;
    pout   = p_all + (size_t)b * 1024 + row0b;
    dfp = P1 + (size_t)b * 1024;                 // slab 0: folded df
    vv = v1; wcp = wc;
  } else {
    int bi = bid - 1024;
    int b = bi >> 2, row0b = (bi & 3) * 64;
    feat   = enc_img_features + ((size_t)b * 256 + row0b) * 1024;
    osrc   = enc_img_outputs  + ((size_t)b * 256 + row0b) * 1024;
    covsrc = coverage_img + (size_t)b * 256 + row0b;
    msk    = nullptr;
    pout   = p_all + 65536 + (size_t)b * 256 + row0b;
    dfp = P1 + 4 * 65536 + (size_t)b * 1024;     // slab 4: folded dfi
    vv = v2; wcp = wci;
  }
  // stage operands: threads 0..255 -> sdf, 256..511 -> sv+swc
  if (tid < 256) {
    sdf[tid] = reinterpret_cast<const f32x4*>(dfp)[tid];
  } else {
    int t = tid - 256;
    sv[t]  = reinterpret_cast<const f32x4*>(vv)[t];
    swc[t] = reinterpret_cast<const f32x4*>(wcp)[t];
  }
  __syncthreads();

  // cov/mask for this wave's 8 rows (rows 16t + 2w + j), packed at lane 2t+j.
  float covv = 0.f, mskv = 1.f;
  if (lane < 8) {
    int rr = 16 * (lane >> 1) + 2 * w + (lane & 1);
    covv = covsrc[rr];
    mskv = msk ? msk[rr] : 1.f;
  }

  // V = sum_a |v_a| (deterministic, identical in every wave)
  float Vp = 0.f;
#pragma unroll
  for (int p = 0; p < 4; ++p) {
    f32x4 t = sv[p * 64 + lane];
    Vp += fabsf(t.x) + fabsf(t.y) + fabsf(t.z) + fabsf(t.w);
  }
#pragma unroll
  for (int o = 32; o > 0; o >>= 1) Vp += __shfl_xor(Vp, o);
  float V = Vp;

  const f32x4* F = reinterpret_cast<const f32x4*>(feat);
  int g2 = tid >> 8;        // 0/1: row parity for phase B
  int aq = tid & 255;       // a-quad for phase B
  const f32x4* O = reinterpret_cast<const f32x4*>(osrc) + aq;
  f32x4 acc4 = {0.f, 0.f, 0.f, 0.f};

#pragma unroll
  for (int t = 0; t < 4; ++t) {
    // ---- A: rows 16t+2w, 16t+2w+1 (both rows' loads issued up front) ----
    int r0 = 16 * t + 2 * w;
    f32x4 c0[4], c1[4];
#pragma unroll
    for (int p = 0; p < 4; ++p) c0[p] = F[(size_t)r0 * 256 + p * 64 + lane];
#pragma unroll
    for (int p = 0; p < 4; ++p) c1[p] = F[(size_t)(r0 + 1) * 256 + p * 64 + lane];
#pragma unroll
    for (int j = 0; j < 2; ++j) {
      float crow = __shfl(covv, 2 * t + j) * covscale;
      float mrow = __shfl(mskv, 2 * t + j);
      float acc = 0.f;
#pragma unroll
      for (int p = 0; p < 4; ++p) {
        f32x4 f  = j ? c1[p] : c0[p];
        f32x4 v4 = sv[p * 64 + lane];
        f32x4 x  = f + sdf[p * 64 + lane] + crow * swc[p * 64 + lane];
        acc += v4.x * ftanh(x.x);
        acc += v4.y * ftanh(x.y);
        acc += v4.z * ftanh(x.z);
        acc += v4.w * ftanh(x.w);
      }
#pragma unroll
      for (int o = 32; o > 0; o >>= 1) acc += __shfl_xor(acc, o);
      if (lane == 0) {
        float p = __expf(acc - V) * mrow;
        pl[r0 + j] = p;
        pout[r0 + j] = p;
      }
    }
    __syncthreads();   // pl[16t..16t+15] complete (next A writes disjoint pl)

    // ---- B: rows 16t+g2, +2, ..., +14 (8 rows/half, 8-deep rotation) ----
    f32x4 buf[8];
#pragma unroll
    for (int jj = 0; jj < 8; ++jj)
      buf[jj] = O[(size_t)(16 * t + g2 + 2 * jj) * 256];
#pragma unroll
    for (int jj = 0; jj < 8; ++jj)
      acc4 += pl[16 * t + g2 + 2 * jj] * buf[jj];
  }

  if (g2 == 1) sacc[aq] = acc4;
  __syncthreads();
  if (g2 == 0) {
    acc4 += sacc[aq];
    *reinterpret_cast<f32x4*>(P4 + (size_t)bid * 1024 + aq * 4) = acc4;
  }
}

// K34 (norm + ctx reduce): block = batch b (64 blocks).
__global__ __launch_bounds__(256) void k34(
    const float* __restrict__ p_all, const float* __restrict__ P4,
    const float* __restrict__ coverage, const float* __restrict__ coverage_img,
    const int* __restrict__ cov_set_p,
    float* __restrict__ out, float* __restrict__ ctx) {
  __shared__ float redT[4], redI[4];
  int b   = blockIdx.x;
  int tid = threadIdx.x;
  float covscale = (float)(*cov_set_p);
  const float* pt = p_all + (size_t)b * 1024;
  const float* pi = p_all + 65536 + (size_t)b * 256;

  float pv[4];
  float st = 0.f;
#pragma unroll
  for (int k = 0; k < 4; ++k) {
    pv[k] = pt[k * 256 + tid];
    st += pv[k];
  }
  float piv = pi[tid];
  float si = piv;
#pragma unroll
  for (int o = 32; o > 0; o >>= 1) {
    st += __shfl_xor(st, o);
    si += __shfl_xor(si, o);
  }
  if ((tid & 63) == 0) {
    redT[tid >> 6] = st;
    redI[tid >> 6] = si;
  }
  __syncthreads();
  float invT = 1.f / (redT[0] + redT[1] + redT[2] + redT[3]);
  float invI = 1.f / (redI[0] + redI[1] + redI[2] + redI[3]);

  const float* covT = coverage + (size_t)b * 1024;
  const float* covI = coverage_img + (size_t)b * 256;
  float* attnT = out + 65536 + (size_t)b * 1024;
  float* covTo = out + 147456 + (size_t)b * 1024;
  float* attnI = out + 131072 + (size_t)b * 256;
  float* covIo = out + 212992 + (size_t)b * 256;
#pragma unroll
  for (int k = 0; k < 4; ++k) {
    int i = k * 256 + tid;
    float at = pv[k] * invT;
    attnT[i] = at;
    covTo[i] = covscale * covT[i] + at;
  }
  {
    float at = piv * invI;
    attnI[tid] = at;
    covIo[tid] = covscale * covI[tid] + at;
  }

  f32x4 accT = {0.f, 0.f, 0.f, 0.f};
#pragma unroll
  for (int c = 0; c < 16; ++c)
    accT += *reinterpret_cast<const f32x4*>(P4 + ((size_t)(b * 16 + c)) * 1024 + tid * 4);
  *reinterpret_cast<f32x4*>(ctx + (size_t)b * 1024 + tid * 4) = accT * invT;

  f32x4 accI = {0.f, 0.f, 0.f, 0.f};
#pragma unroll
  for (int c = 0; c < 4; ++c)
    accI += *reinterpret_cast<const f32x4*>(P4 + ((size_t)(1024 + b * 4 + c)) * 1024 + tid * 4);
  *reinterpret_cast<f32x4*>(ctx + 65536 + (size_t)b * 1024 + tid * 4) = accI * invI;
}

// K5: partials of ctx_t@WA (m=0), ctx_i@WB (m=1). grid = 128 blocks
// (m x 16 bg x 4 kq), 4 batch rows each.
__global__ __launch_bounds__(256) void k5_gemm(
    const float* __restrict__ ctx,
    const float* __restrict__ WA, const float* __restrict__ WB,
    float* __restrict__ P5) {
  int bid = blockIdx.x;            // 0..127
  int m   = bid >> 6;              // 0..1
  int bg  = (bid >> 2) & 15;       // 0..15
  int kq  = bid & 3;
  const float* W = m ? WB : WA;
  const float* dbase = ctx + (size_t)m * 65536 + kq * 256;
  const float* Wrow  = W + (size_t)(kq * 256) * A_DIM + threadIdx.x * 4;

  f32x4 acc[4];
#pragma unroll
  for (int i = 0; i < 4; ++i) acc[i] = (f32x4){0.f, 0.f, 0.f, 0.f};

#pragma unroll 2
  for (int k4 = 0; k4 < 256; k4 += 4) {
    f32x4 w0 = *reinterpret_cast<const f32x4*>(Wrow + (size_t)(k4 + 0) * A_DIM);
    f32x4 w1 = *reinterpret_cast<const f32x4*>(Wrow + (size_t)(k4 + 1) * A_DIM);
    f32x4 w2 = *reinterpret_cast<const f32x4*>(Wrow + (size_t)(k4 + 2) * A_DIM);
    f32x4 w3 = *reinterpret_cast<const f32x4*>(Wrow + (size_t)(k4 + 3) * A_DIM);
#pragma unroll
    for (int i = 0; i < 4; ++i) {
      int b = bg * 4 + i;
      f32x4 d = *reinterpret_cast<const f32x4*>(dbase + (size_t)b * A_DIM + k4);
      acc[i] += d.x * w0;
      acc[i] += d.y * w1;
      acc[i] += d.z * w2;
      acc[i] += d.w * w3;
    }
  }
#pragma unroll
  for (int i = 0; i < 4; ++i) {
    int b = bg * 4 + i;
    *reinterpret_cast<f32x4*>(
        P5 + ((size_t)(m * 4 + kq) * 64 + b) * A_DIM + threadIdx.x * 4) = acc[i];
  }
}

// K5b: ctx_mm = v3*tanh(g3+ctx_t@WA)*ctx_t + v4*tanh(g4+ctx_i@WB)*ctx_i
__global__ __launch_bounds__(256) void k5b_final(
    const float* __restrict__ P5, const float* __restrict__ P1,
    const float* __restrict__ b3, const float* __restrict__ b4,
    const float* __restrict__ ctx,
    const float* __restrict__ v3, const float* __restrict__ v4,
    float* __restrict__ out) {
  int tid = blockIdx.x * 256 + threadIdx.x;  // 0..65535
  int a = tid & 1023;
  size_t base = tid;
  float sA = P5[base] + P5[base + 65536] + P5[base + 2 * 65536] + P5[base + 3 * 65536];
  float sB = P5[base + 4 * 65536] + P5[base + 5 * 65536] + P5[base + 6 * 65536] +
             P5[base + 7 * 65536];
  float g3v = P1[8 * 65536 + base] + P1[9 * 65536 + base] +
              P1[10 * 65536 + base] + P1[11 * 65536 + base] + b3[a];
  float g4v = P1[12 * 65536 + base] + P1[13 * 65536 + base] +
              P1[14 * 65536 + base] + P1[15 * 65536 + base] + b4[a];
  float ct = ctx[base];
  float ci = ctx[65536 + base];
  float beta1 = v3[a] * ftanh(g3v + sA);
  float beta2 = v4[a] * ftanh(g4v + sB);
  out[tid] = beta1 * ct + beta2 * ci;
}

extern "C" void kernel_launch(void* const* d_in, const int* in_sizes, int n_in,
                              void* d_out, int out_size, void* d_ws, size_t ws_size,
                              hipStream_t stream) {
  const float* h0            = (const float*)d_in[0];
  const float* h1            = (const float*)d_in[1];
  const float* enc_outputs   = (const float*)d_in[2];
  const float* enc_features  = (const float*)d_in[3];
  const float* enc_mask      = (const float*)d_in[4];
  const float* coverage      = (const float*)d_in[5];
  const float* enc_img_outs  = (const float*)d_in[6];
  const float* enc_img_feats = (const float*)d_in[7];
  // d_in[8] = img_mask (unused by reference)
  const float* coverage_img  = (const float*)d_in[9];
  const int*   cov_set       = (const int*)d_in[10];
  const float* W1 = (const float*)d_in[11];
  const float* b1 = (const float*)d_in[12];
  const float* W2 = (const float*)d_in[13];
  const float* b2 = (const float*)d_in[14];
  const float* W3 = (const float*)d_in[15];
  const float* b3 = (const float*)d_in[16];
  const float* W4 = (const float*)d_in[17];
  const float* b4 = (const float*)d_in[18];
  const float* WA = (const float*)d_in[19];
  const float* WB = (const float*)d_in[20];
  const float* v1 = (const float*)d_in[21];
  const float* v2 = (const float*)d_in[22];
  const float* v3 = (const float*)d_in[23];
  const float* v4 = (const float*)d_in[24];
  const float* wc  = (const float*)d_in[25];
  const float* wci = (const float*)d_in[26];

  float* out = (float*)d_out;
  float* ws  = (float*)d_ws;

  float* P1    = ws + WS_P1_OFF;
  float* P4    = ws + WS_P4_OFF;
  float* P5    = ws + WS_P5_OFF;   // reuses P4 region (P4 dead after k34)
  float* p_all = ws + WS_PALL_OFF;
  float* ctx   = ws + WS_CTX_OFF;

  k1_gemm<<<dim3(256), dim3(256), 0, stream>>>(h0, h1, W1, W2, W3, W4, P1);
  k1b_fold<<<dim3(512), dim3(256), 0, stream>>>(P1, b1, b2);
  k24_fused<<<dim3(1280), dim3(512), 0, stream>>>(
      enc_features, enc_img_feats, enc_outputs, enc_img_outs,
      coverage, coverage_img, enc_mask, P1,
      v1, v2, wc, wci, cov_set, p_all, P4);
  k34<<<dim3(64), dim3(256), 0, stream>>>(p_all, P4, coverage, coverage_img,
                                          cov_set, out, ctx);
  k5_gemm<<<dim3(128), dim3(256), 0, stream>>>(ctx, WA, WB, P5);
  k5b_final<<<dim3(256), dim3(256), 0, stream>>>(P5, P1, b3, b4, ctx, v3, v4, out);
}